// Round 1
// baseline (981.166 us; speedup 1.0000x reference)
//
#include <hip/hip_runtime.h>
#include <math.h>

// Problem constants (from reference file; spatial_shapes/level_start_index are
// static in the reference, hardcoded here).
constexpr int kBS = 2;
constexpr int kNQ = 20197;
constexpr int kNV = 20197;
constexpr int kE  = 256;
constexpr int kNH = 8;
constexpr int kD  = 32;   // kE / kNH
constexpr int kM  = kBS * kNQ;  // 40394 rows for all GEMMs

__constant__ const int kLH[4] = {100, 50, 25, 13};
__constant__ const int kLW[4] = {152, 76, 38, 19};
__constant__ const int kLS[4] = {0, 15200, 19000, 19950};

// ---------------------------------------------------------------------------
// Tiled fp32 GEMM: C[M,N] = A[M,K] @ B[K,N] + bias[N] (+ res[M,N] if res!=0)
// 64x64 tile, 256 threads, 4x4 per thread, BK=16.
// ---------------------------------------------------------------------------
__global__ __launch_bounds__(256) void gemm_bias_res(
    const float* __restrict__ A, const float* __restrict__ B,
    const float* __restrict__ bias, const float* __restrict__ res,
    float* __restrict__ C, int M, int N, int K)
{
    // As padded to 68 floats/row: 272 B row stride -> 16B-aligned b128 reads,
    // store bank pattern (4*k+m)%32 is 2-way (free per m136).
    __shared__ float As[16][68];
    __shared__ float Bs[16][64];
    const int t  = threadIdx.x;
    const int m0 = blockIdx.y * 64;
    const int n0 = blockIdx.x * 64;
    const int tx = t & 15;    // output col group
    const int ty = t >> 4;    // output row group
    const int la_k = t & 15;  // A-load k
    const int la_m = t >> 4;  // A-load row base (stride 16, 4 passes)
    const int lb_n = t & 63;  // B-load col
    const int lb_k = t >> 6;  // B-load k base (stride 4, 4 passes)

    float acc[4][4] = {};

    for (int k0 = 0; k0 < K; k0 += 16) {
        #pragma unroll
        for (int i = 0; i < 4; ++i) {
            int m = m0 + la_m + i * 16;
            As[la_k][la_m + i * 16] = (m < M) ? A[(size_t)m * K + (k0 + la_k)] : 0.f;
        }
        #pragma unroll
        for (int i = 0; i < 4; ++i) {
            int kk = lb_k + i * 4;
            Bs[kk][lb_n] = B[(size_t)(k0 + kk) * N + (n0 + lb_n)];
        }
        __syncthreads();
        #pragma unroll
        for (int kk = 0; kk < 16; ++kk) {
            float a[4], b[4];
            #pragma unroll
            for (int i = 0; i < 4; ++i) a[i] = As[kk][ty * 4 + i];
            #pragma unroll
            for (int j = 0; j < 4; ++j) b[j] = Bs[kk][tx * 4 + j];
            #pragma unroll
            for (int i = 0; i < 4; ++i)
                #pragma unroll
                for (int j = 0; j < 4; ++j)
                    acc[i][j] += a[i] * b[j];
        }
        __syncthreads();
    }

    #pragma unroll
    for (int i = 0; i < 4; ++i) {
        int m = m0 + ty * 4 + i;
        if (m >= M) continue;
        #pragma unroll
        for (int j = 0; j < 4; ++j) {
            int n = n0 + tx * 4 + j;
            float vv = acc[i][j] + bias[n];
            if (res) vv += res[(size_t)m * N + n];
            C[(size_t)m * N + n] = vv;
        }
    }
}

// ---------------------------------------------------------------------------
// In-place softmax over groups of 16 (per (row, head)).
// ---------------------------------------------------------------------------
__global__ __launch_bounds__(256) void softmax16(float* __restrict__ a, int total)
{
    int g = blockIdx.x * blockDim.x + threadIdx.x;
    if (g >= total) return;
    float* p = a + (size_t)g * 16;
    float v[16];
    float mx = -1e30f;
    #pragma unroll
    for (int i = 0; i < 16; ++i) { v[i] = p[i]; mx = fmaxf(mx, v[i]); }
    float sum = 0.f;
    #pragma unroll
    for (int i = 0; i < 16; ++i) { v[i] = __expf(v[i] - mx); sum += v[i]; }
    float inv = 1.f / sum;
    #pragma unroll
    for (int i = 0; i < 16; ++i) p[i] = v[i] * inv;
}

// ---------------------------------------------------------------------------
// Deformable sampling. One block per (b,q); 256 threads = 8 heads x 32 chans.
// mid may alias sofs: row is staged to LDS before the final write.
// ---------------------------------------------------------------------------
__global__ __launch_bounds__(256) void msda_sample(
    const float* __restrict__ v,     // (BS, NV, 256): chan = h*32+c
    const float* __restrict__ sofs,  // (M, 256)
    const float* __restrict__ aw,    // (M, 128), softmaxed
    const float* __restrict__ rp,    // (M, 8)
    float* __restrict__ mid)         // (M, 256)
{
    const int bq = blockIdx.x;       // 0..M-1
    const int b  = bq / kNQ;
    const int t  = threadIdx.x;
    const int h  = t >> 5;
    const int c  = t & 31;

    __shared__ float sSo[256];
    __shared__ float sAw[128];
    __shared__ float sRp[8];
    sSo[t] = sofs[(size_t)bq * 256 + t];
    if (t < 128) sAw[t] = aw[(size_t)bq * 128 + t];
    if (t < 8)   sRp[t] = rp[(size_t)bq * 8 + t];
    __syncthreads();

    float acc = 0.f;
    const float* vb = v + ((size_t)b * kNV) * 256 + h * 32 + c;

    #pragma unroll
    for (int l = 0; l < 4; ++l) {
        const int hh = kLH[l], ww = kLW[l];
        const float fw = (float)ww, fh = (float)hh;
        const float rx = sRp[l * 2 + 0], ry = sRp[l * 2 + 1];
        const float* vl = vb + (size_t)kLS[l] * 256;
        #pragma unroll
        for (int p = 0; p < 4; ++p) {
            const int soi = h * 32 + l * 8 + p * 2;
            // mirror reference arithmetic: loc = rp + so/norm; x = loc*w - 0.5
            float locx = rx + sSo[soi + 0] / fw;
            float locy = ry + sSo[soi + 1] / fh;
            float x = locx * fw - 0.5f;
            float y = locy * fh - 0.5f;
            float xf = floorf(x), yf = floorf(y);
            int x0 = (int)xf, y0 = (int)yf;
            float wx1 = x - xf, wy1 = y - yf;
            float wx0 = 1.f - wx1, wy0 = 1.f - wy1;
            float w = sAw[h * 16 + l * 4 + p];

            bool vx0 = (x0 >= 0) && (x0 < ww);
            bool vx1 = (x0 + 1 >= 0) && (x0 + 1 < ww);
            bool vy0 = (y0 >= 0) && (y0 < hh);
            bool vy1 = (y0 + 1 >= 0) && (y0 + 1 < hh);
            int cx0 = min(max(x0, 0), ww - 1);
            int cx1 = min(max(x0 + 1, 0), ww - 1);
            int cy0 = min(max(y0, 0), hh - 1);
            int cy1 = min(max(y0 + 1, 0), hh - 1);

            float s00 = 0.f, s10 = 0.f, s01 = 0.f, s11 = 0.f;
            if (vy0) {
                const float* row = vl + (size_t)(cy0 * ww) * 256;
                if (vx0) s00 = row[(size_t)cx0 * 256];
                if (vx1) s10 = row[(size_t)cx1 * 256];
            }
            if (vy1) {
                const float* row = vl + (size_t)(cy1 * ww) * 256;
                if (vx0) s01 = row[(size_t)cx0 * 256];
                if (vx1) s11 = row[(size_t)cx1 * 256];
            }
            acc += w * (s00 * (wx0 * wy0) + s10 * (wx1 * wy0) +
                        s01 * (wx0 * wy1) + s11 * (wx1 * wy1));
        }
    }
    mid[(size_t)bq * 256 + t] = acc;
}

// ---------------------------------------------------------------------------
extern "C" void kernel_launch(void* const* d_in, const int* in_sizes, int n_in,
                              void* d_out, int out_size, void* d_ws, size_t ws_size,
                              hipStream_t stream)
{
    const float* query = (const float*)d_in[0];
    const float* value = (const float*)d_in[1];
    const float* rp    = (const float*)d_in[2];
    // d_in[3] spatial_shapes, d_in[4] level_start_index: static, hardcoded
    const float* Wv  = (const float*)d_in[5];
    const float* bv  = (const float*)d_in[6];
    const float* Wso = (const float*)d_in[7];
    const float* bso = (const float*)d_in[8];
    const float* Waw = (const float*)d_in[9];
    const float* baw = (const float*)d_in[10];
    const float* Wo  = (const float*)d_in[11];
    const float* bo  = (const float*)d_in[12];

    float* out = (float*)d_out;

    // Scratch layout:
    //   v   -> d_out (dead before final GEMM overwrites d_out)
    //   so  -> ws[0 : M*256]  (reused in place as mid by msda_sample)
    //   aw  -> ws[M*256 : M*256 + M*128]
    float* v  = out;
    float* so = (float*)d_ws;
    float* aw = so + (size_t)kM * 256;
    float* mid = so;

    dim3 blk(256);
    dim3 g256(256 / 64, (kM + 63) / 64);
    dim3 g128(128 / 64, (kM + 63) / 64);

    hipLaunchKernelGGL(gemm_bias_res, g256, blk, 0, stream,
                       value, Wv, bv, (const float*)nullptr, v, kM, 256, 256);
    hipLaunchKernelGGL(gemm_bias_res, g256, blk, 0, stream,
                       query, Wso, bso, (const float*)nullptr, so, kM, 256, 256);
    hipLaunchKernelGGL(gemm_bias_res, g128, blk, 0, stream,
                       query, Waw, baw, (const float*)nullptr, aw, kM, 128, 256);
    hipLaunchKernelGGL(softmax16, dim3((kM * kNH + 255) / 256), blk, 0, stream,
                       aw, kM * kNH);
    hipLaunchKernelGGL(msda_sample, dim3(kM), blk, 0, stream,
                       v, so, aw, rp, mid);
    hipLaunchKernelGGL(gemm_bias_res, g256, blk, 0, stream,
                       mid, Wo, bo, query, out, kM, 256, 256);
}

// Round 2
// 336.077 us; speedup vs baseline: 2.9195x; 2.9195x over previous
//
#include <hip/hip_runtime.h>
#include <hip/hip_bf16.h>
#include <math.h>

constexpr int kBS = 2;
constexpr int kNQ = 20197;
constexpr int kNV = 20197;
constexpr int kNH = 8;
constexpr int kM  = kBS * kNQ;   // 40394
constexpr int kMpad = 40448;     // 316 * 128, slack rows for global_load_lds

__constant__ int cLH[4] = {100, 50, 25, 13};
__constant__ int cLW[4] = {152, 76, 38, 19};
__constant__ int cLS[4] = {0, 15200, 19000, 19950};

typedef __bf16 bf16x8 __attribute__((ext_vector_type(8)));
typedef float  f32x4  __attribute__((ext_vector_type(4)));

__device__ __forceinline__ unsigned short f2bf(float x) {
    unsigned u = __float_as_uint(x);
    return (unsigned short)((u + 0x7fffu + ((u >> 16) & 1u)) >> 16);
}
__device__ __forceinline__ unsigned pack2(float a, float b) {
    return (unsigned)f2bf(a) | ((unsigned)f2bf(b) << 16);
}
__device__ __forceinline__ void gload_lds16(const void* g, void* s) {
    __builtin_amdgcn_global_load_lds(
        (const __attribute__((address_space(1))) void*)g,
        (__attribute__((address_space(3))) void*)s, 16, 0, 0);
}

// ---------------------------------------------------------------------------
// Weight prep: src is K x N fp32 (K=256), dst is N x K bf16 (B^T).
// ---------------------------------------------------------------------------
__global__ __launch_bounds__(256) void prep_wt(
    const float* __restrict__ src, unsigned short* __restrict__ dst,
    int total, int N)
{
    int i = blockIdx.x * 256 + threadIdx.x;
    if (i >= total) return;
    int n = i >> 8, k = i & 255;   // K == 256
    dst[i] = f2bf(src[k * N + n]);
}

// ---------------------------------------------------------------------------
// bf16 MFMA GEMM: C[M,N] = A[M,256] @ BT[N,256]^T + bias (+res).
// 128x128 tile, 256 threads (4 waves in 2x2), BK=32, 16x16x32 MFMA.
// A: fp32 (converted in staging, row-guarded) or bf16 (global_load_lds,
// requires Mpad slack). BT: bf16 N x 256, staged via global_load_lds.
// ---------------------------------------------------------------------------
template<bool ABF16, bool OUTBF16, bool RES>
__global__ __launch_bounds__(256) void gemm_mfma(
    const void* __restrict__ Av, const __hip_bfloat16* __restrict__ BT,
    const float* __restrict__ bias, const float* __restrict__ res,
    void* __restrict__ Cv, int M, int N)
{
    constexpr int APITCH = ABF16 ? 32 : 40;   // bf16 elems per As row
    __shared__ __hip_bfloat16 As[128 * APITCH];
    __shared__ __hip_bfloat16 Bs[128 * 32];

    const int t = threadIdx.x;
    const int wave = t >> 6, lane = t & 63;
    const int quad = lane >> 4, l16 = lane & 15;
    const int mw = (wave & 1) * 64, nw = (wave >> 1) * 64;
    const int m0 = blockIdx.y * 128, n0 = blockIdx.x * 128;
    const int sm = t >> 1;          // fp32-A staging row
    const int sh = (t & 1) * 16;    // fp32-A staging k-half

    f32x4 acc[4][4] = {};

    for (int k0 = 0; k0 < 256; k0 += 32) {
        __syncthreads();
        // --- stage B (always bf16, lane-contiguous -> global_load_lds) ---
        {
            const char* bt = (const char*)BT;
            #pragma unroll
            for (int j = 0; j < 2; ++j) {
                int off = j * 4096 + t * 16;
                int row = off >> 6, kb = off & 63;
                gload_lds16(bt + (size_t)(n0 + row) * 512 + k0 * 2 + kb,
                            (char*)Bs + off);
            }
        }
        // --- stage A ---
        if constexpr (ABF16) {
            const char* ab = (const char*)Av;
            #pragma unroll
            for (int j = 0; j < 2; ++j) {
                int off = j * 4096 + t * 16;
                int row = off >> 6, kb = off & 63;
                gload_lds16(ab + (size_t)(m0 + row) * 512 + k0 * 2 + kb,
                            (char*)As + off);
            }
        } else {
            const float* af = (const float*)Av;
            float4 f0 = make_float4(0.f, 0.f, 0.f, 0.f), f1 = f0, f2 = f0, f3 = f0;
            if (m0 + sm < M) {
                const float4* p = (const float4*)(af + (size_t)(m0 + sm) * 256 + k0 + sh);
                f0 = p[0]; f1 = p[1]; f2 = p[2]; f3 = p[3];
            }
            uint4 q0 = make_uint4(pack2(f0.x, f0.y), pack2(f0.z, f0.w),
                                  pack2(f1.x, f1.y), pack2(f1.z, f1.w));
            uint4 q1 = make_uint4(pack2(f2.x, f2.y), pack2(f2.z, f2.w),
                                  pack2(f3.x, f3.y), pack2(f3.z, f3.w));
            uint4* dst = (uint4*)(void*)&As[sm * APITCH + sh];
            dst[0] = q0; dst[1] = q1;
        }
        __syncthreads();
        // --- compute: 4 A-frags + 4 B-frags + 16 MFMA ---
        bf16x8 afr[4], bfr[4];
        #pragma unroll
        for (int mt = 0; mt < 4; ++mt)
            afr[mt] = *(const bf16x8*)(const void*)&As[(mw + mt * 16 + l16) * APITCH + quad * 8];
        #pragma unroll
        for (int nt = 0; nt < 4; ++nt)
            bfr[nt] = *(const bf16x8*)(const void*)&Bs[(nw + nt * 16 + l16) * 32 + quad * 8];
        #pragma unroll
        for (int mt = 0; mt < 4; ++mt)
            #pragma unroll
            for (int nt = 0; nt < 4; ++nt)
                acc[mt][nt] = __builtin_amdgcn_mfma_f32_16x16x32_bf16(
                    afr[mt], bfr[nt], acc[mt][nt], 0, 0, 0);
    }

    // --- epilogue: C/D layout col=lane&15, row=quad*4+reg ---
    #pragma unroll
    for (int nt = 0; nt < 4; ++nt) {
        int col = n0 + nw + nt * 16 + l16;
        float bvv = bias[col];
        #pragma unroll
        for (int mt = 0; mt < 4; ++mt) {
            #pragma unroll
            for (int i = 0; i < 4; ++i) {
                int row = m0 + mw + mt * 16 + quad * 4 + i;
                if (row < M) {
                    float val = acc[mt][nt][i] + bvv;
                    if constexpr (RES) val += res[(size_t)row * N + col];
                    if constexpr (OUTBF16)
                        ((unsigned short*)Cv)[(size_t)row * N + col] = f2bf(val);
                    else
                        ((float*)Cv)[(size_t)row * N + col] = val;
                }
            }
        }
    }
}

// ---------------------------------------------------------------------------
// Sampler: 1 block (128 threads) per (b,q).
// Phase 1: thread t = h*16+l*4+p computes that point's softmax weight,
//          4 clamped corner offsets, 4 validity-folded weights -> LDS.
// Phase 2: thread (h = t>>4, chan pair c=2*(t&15)) gathers bf16x2 and
//          accumulates; writes mid bf16.
// ---------------------------------------------------------------------------
__global__ __launch_bounds__(128) void msda_sample(
    const __hip_bfloat16* __restrict__ v,    // (BS*NV, 256) bf16
    const float* __restrict__ so,            // (M, 256)
    const float* __restrict__ logits,        // (M, 128) pre-softmax
    const float* __restrict__ rp,            // (M, 4, 2)
    __hip_bfloat16* __restrict__ mid)        // (Mpad, 256) bf16
{
    const int bq = blockIdx.x;
    const int b  = bq >= kNQ;
    const int t  = threadIdx.x;

    __shared__ int   sOff[128 * 5];
    __shared__ float sW[128 * 5];

    {   // phase 1
        const int h = t >> 4, l = (t >> 2) & 3;
        float2 sv = *(const float2*)(so + (size_t)bq * 256 + 2 * t);
        float  aa = logits[(size_t)bq * 128 + t];
        float2 rr = *(const float2*)(rp + (size_t)bq * 8 + l * 2);
        // softmax over the 16 lanes of this head (lane groups are aligned)
        float mx = aa;
        #pragma unroll
        for (int s = 8; s >= 1; s >>= 1) mx = fmaxf(mx, __shfl_xor(mx, s, 16));
        float e = __expf(aa - mx);
        float sum = e;
        #pragma unroll
        for (int s = 8; s >= 1; s >>= 1) sum += __shfl_xor(sum, s, 16);
        float w = e / sum;

        const int ww = cLW[l], hh = cLH[l];
        const float fw = (float)ww, fh = (float)hh;
        float x = rr.x * fw + sv.x - 0.5f;   // == (rx + so/w)*w - 0.5
        float y = rr.y * fh + sv.y - 0.5f;
        float xf = floorf(x), yf = floorf(y);
        int x0 = (int)xf, y0 = (int)yf;
        float wx1 = x - xf, wx0 = 1.f - wx1;
        float wy1 = y - yf, wy0 = 1.f - wy1;
        bool vx0 = (x0 >= 0) & (x0 < ww);
        bool vx1 = (x0 >= -1) & (x0 + 1 < ww);
        bool vy0 = (y0 >= 0) & (y0 < hh);
        bool vy1 = (y0 >= -1) & (y0 + 1 < hh);
        int cx0 = min(max(x0, 0), ww - 1);
        int cx1 = min(max(x0 + 1, 0), ww - 1);
        int cy0 = min(max(y0, 0), hh - 1);
        int cy1 = min(max(y0 + 1, 0), hh - 1);
        int base = cLS[l] * 256 + h * 32;
        sOff[t * 5 + 0] = base + (cy0 * ww + cx0) * 256;
        sOff[t * 5 + 1] = base + (cy0 * ww + cx1) * 256;
        sOff[t * 5 + 2] = base + (cy1 * ww + cx0) * 256;
        sOff[t * 5 + 3] = base + (cy1 * ww + cx1) * 256;
        sW[t * 5 + 0] = (vx0 & vy0) ? w * wx0 * wy0 : 0.f;
        sW[t * 5 + 1] = (vx1 & vy0) ? w * wx1 * wy0 : 0.f;
        sW[t * 5 + 2] = (vx0 & vy1) ? w * wx0 * wy1 : 0.f;
        sW[t * 5 + 3] = (vx1 & vy1) ? w * wx1 * wy1 : 0.f;
    }
    __syncthreads();

    // phase 2
    const int h = t >> 4, c = (t & 15) * 2;
    const __hip_bfloat16* vb = v + (size_t)b * kNV * 256 + c;
    float accx = 0.f, accy = 0.f;
    const int p0 = h * 16;
    #pragma unroll 4
    for (int pp = 0; pp < 16; ++pp) {
        const int idx = (p0 + pp) * 5;
        #pragma unroll
        for (int k2 = 0; k2 < 4; ++k2) {
            float wgt = sW[idx + k2];
            int   off = sOff[idx + k2];
            unsigned u = *(const unsigned*)(const void*)(vb + off);
            float lo = __uint_as_float(u << 16);
            float hi = __uint_as_float(u & 0xffff0000u);
            accx += wgt * lo;
            accy += wgt * hi;
        }
    }
    unsigned pk = pack2(accx, accy);
    *(unsigned*)(void*)(mid + (size_t)bq * 256 + h * 32 + c) = pk;
}

// ---------------------------------------------------------------------------
extern "C" void kernel_launch(void* const* d_in, const int* in_sizes, int n_in,
                              void* d_out, int out_size, void* d_ws, size_t ws_size,
                              hipStream_t stream)
{
    const float* query = (const float*)d_in[0];
    const float* value = (const float*)d_in[1];
    const float* rp    = (const float*)d_in[2];
    const float* Wv  = (const float*)d_in[5];
    const float* bv  = (const float*)d_in[6];
    const float* Wso = (const float*)d_in[7];
    const float* bso = (const float*)d_in[8];
    const float* Waw = (const float*)d_in[9];
    const float* baw = (const float*)d_in[10];
    const float* Wo  = (const float*)d_in[11];
    const float* bo  = (const float*)d_in[12];

    // d_out overlay until final GEMM: v_b (M*512 B) + logits (M*512 B) == out bytes
    char* out8 = (char*)d_out;
    __hip_bfloat16* v_b    = (__hip_bfloat16*)out8;
    float*          logits = (float*)(out8 + (size_t)kM * 512);

    // ws: so fp32 (M*1024 B) | mid bf16 (Mpad*512 B) | 4 transposed weights
    char* ws8 = (char*)d_ws;
    float*          so    = (float*)ws8;
    __hip_bfloat16* mid_b = (__hip_bfloat16*)(ws8 + (size_t)kM * 1024);
    __hip_bfloat16* WvT   = (__hip_bfloat16*)(ws8 + (size_t)kM * 1024 + (size_t)kMpad * 512);
    __hip_bfloat16* WsoT  = WvT  + 256 * 256;
    __hip_bfloat16* WawT  = WsoT + 256 * 256;
    __hip_bfloat16* WoT   = WawT + 128 * 256;

    hipLaunchKernelGGL(prep_wt, dim3(256), dim3(256), 0, stream, Wv,  (unsigned short*)WvT,  256 * 256, 256);
    hipLaunchKernelGGL(prep_wt, dim3(256), dim3(256), 0, stream, Wso, (unsigned short*)WsoT, 256 * 256, 256);
    hipLaunchKernelGGL(prep_wt, dim3(128), dim3(256), 0, stream, Waw, (unsigned short*)WawT, 128 * 256, 128);
    hipLaunchKernelGGL(prep_wt, dim3(256), dim3(256), 0, stream, Wo,  (unsigned short*)WoT,  256 * 256, 256);

    dim3 blk(256);
    dim3 g2(2, 316), g1(1, 316);
    hipLaunchKernelGGL((gemm_mfma<false, true,  false>), g2, blk, 0, stream,
                       (const void*)value, WvT, bv, (const float*)nullptr, (void*)v_b, kM, 256);
    hipLaunchKernelGGL((gemm_mfma<false, false, false>), g2, blk, 0, stream,
                       (const void*)query, WsoT, bso, (const float*)nullptr, (void*)so, kM, 256);
    hipLaunchKernelGGL((gemm_mfma<false, false, false>), g1, blk, 0, stream,
                       (const void*)query, WawT, baw, (const float*)nullptr, (void*)logits, kM, 128);
    hipLaunchKernelGGL(msda_sample, dim3(kM), dim3(128), 0, stream,
                       v_b, so, logits, rp, mid_b);
    hipLaunchKernelGGL((gemm_mfma<true,  false, true>), g2, blk, 0, stream,
                       (const void*)mid_b, WoT, bo, query, d_out, kM, 256);
}